// Round 11
// baseline (237.007 us; speedup 1.0000x reference)
//
#include <hip/hip_runtime.h>

#define B_ 2048
#define T_ 256
#define F_ 64
#define EMB_ 16
#define UNITS_ 32
#define L2E 1.44269504f
#define MAGIC 0x51E5C0DEu

typedef __attribute__((ext_vector_type(8))) short bf16x8;
typedef __attribute__((ext_vector_type(4))) float f32x4;

__device__ __forceinline__ unsigned short f2bf(float f) {  // RNE float->bf16
    unsigned u = __float_as_uint(f);
    return (unsigned short)((u + 0x7FFFu + ((u >> 16) & 1u)) >> 16);
}
__device__ __forceinline__ float fast_sigmoid(float x) {
    return __builtin_amdgcn_rcpf(1.0f + __builtin_amdgcn_exp2f(-L2E * x));
}

// One dispatch, two roles:
//   blocks 0..1023  : embed (4 independent waves/block, chunk-major task order)
//   blocks 1024..1151: r5 recurrence (verified 62us core), consuming e via
//                      per-(tile,chunk) release/acquire flags (agent scope).
// Flags: e_ws + 16MiB, one uint per (tile,chunk) = 128*32. Embed writes MAGIC
// after its stores are drained; rec prefetches flag c+1 while consuming chunk
// c (register-resident check), spins only at startup; resets its 32 flags to
// 0 at the end -> deterministic across replays (poison 0xAA.. != MAGIC).
__global__ __launch_bounds__(256) void lstm_all(
    const float* __restrict__ x,
    const float* __restrict__ Wemb, const float* __restrict__ bemb,
    const float* __restrict__ Wf, const float* __restrict__ bfv,
    const float* __restrict__ Wi, const float* __restrict__ biv,
    const float* __restrict__ Wc, const float* __restrict__ bcv,
    const float* __restrict__ Wo, const float* __restrict__ bov,
    const float* __restrict__ Wout, const float* __restrict__ bout,
    unsigned int* __restrict__ e_ws, unsigned int* __restrict__ flags,
    float* __restrict__ out)
{
    __shared__ unsigned short slab[4][2][16][72];   // embed role (per wave)
    __shared__ unsigned short hx[2][16][36];        // rec role
    __shared__ float pred[4][16];

    const int tid = threadIdx.x;
    const int w = tid >> 6;
    const int lane = tid & 63;
    const int g = lane >> 4, m15 = lane & 15;

    if (blockIdx.x < 1024) {
        // ================= EMBED ROLE =================
        const int id = blockIdx.x * 4 + w;     // chunk-major: chunk = id/128
        const int chunk = id >> 7;
        const int tile = id & 127;
        const int t0 = chunk * 8;

        bf16x8 A1, A2;
        #pragma unroll
        for (int j = 0; j < 4; ++j) {
            A1[j]     = (short)f2bf(Wemb[(4 * g + j) * EMB_ + m15]);
            A1[j + 4] = (short)f2bf(Wemb[(16 + 4 * g + j) * EMB_ + m15]);
            A2[j]     = (short)f2bf(Wemb[(32 + 4 * g + j) * EMB_ + m15]);
            A2[j + 4] = (short)f2bf(Wemb[(48 + 4 * g + j) * EMB_ + m15]);
        }
        f32x4 bc;
        #pragma unroll
        for (int r = 0; r < 4; ++r) bc[r] = bemb[4 * g + r];

        const int sr = lane >> 2, sc = lane & 3;
        const float* xs = x + (size_t)(tile * 16 + sr) * T_ * F_ + sc * 16;

        float4 rld[4], nld[4];
        {
            const float4* p = (const float4*)(xs + (size_t)t0 * F_);
            rld[0] = p[0]; rld[1] = p[1]; rld[2] = p[2]; rld[3] = p[3];
        }
        #pragma unroll
        for (int i = 0; i < 9; ++i) {
            if (i < 7) {
                const float4* p = (const float4*)(xs + (size_t)(t0 + i + 1) * F_);
                nld[0] = p[0]; nld[1] = p[1]; nld[2] = p[2]; nld[3] = p[3];
            }
            if (i < 8) {
                const float* f = (const float*)rld;
                unsigned u[8];
                #pragma unroll
                for (int k = 0; k < 8; ++k)
                    u[k] = (unsigned)f2bf(f[2 * k]) | ((unsigned)f2bf(f[2 * k + 1]) << 16);
                uint4* d = (uint4*)&slab[w][i & 1][sr][sc * 16];
                d[0] = make_uint4(u[0], u[1], u[2], u[3]);
                d[1] = make_uint4(u[4], u[5], u[6], u[7]);
            }
            if (i > 0) {
                const unsigned short* row = &slab[w][(i - 1) & 1][m15][0];
                ushort4 l1 = *(const ushort4*)(row + 4 * g);
                ushort4 h1 = *(const ushort4*)(row + 16 + 4 * g);
                ushort4 l2 = *(const ushort4*)(row + 32 + 4 * g);
                ushort4 h2 = *(const ushort4*)(row + 48 + 4 * g);
                bf16x8 B1 = {(short)l1.x, (short)l1.y, (short)l1.z, (short)l1.w,
                             (short)h1.x, (short)h1.y, (short)h1.z, (short)h1.w};
                bf16x8 B2 = {(short)l2.x, (short)l2.y, (short)l2.z, (short)l2.w,
                             (short)h2.x, (short)h2.y, (short)h2.z, (short)h2.w};
                f32x4 acc = __builtin_amdgcn_mfma_f32_16x16x32_bf16(A1, B1, bc, 0, 0, 0);
                acc = __builtin_amdgcn_mfma_f32_16x16x32_bf16(A2, B2, acc, 0, 0, 0);
                unsigned u0 = (unsigned)f2bf(fast_sigmoid(acc[0])) |
                              ((unsigned)f2bf(fast_sigmoid(acc[1])) << 16);
                unsigned u1 = (unsigned)f2bf(fast_sigmoid(acc[2])) |
                              ((unsigned)f2bf(fast_sigmoid(acc[3])) << 16);
                size_t idx = (((size_t)tile * T_ + (t0 + i - 1)) * 64 + lane) * 2;
                *(uint2*)(e_ws + idx) = make_uint2(u0, u1);
            }
            #pragma unroll
            for (int k = 0; k < 4; ++k) rld[k] = nld[k];
        }
        // publish: stores drained, then release flag (device scope)
        asm volatile("s_waitcnt vmcnt(0)" ::: "memory");
        if (lane == 0)
            __hip_atomic_store(&flags[tile * 32 + chunk], MAGIC,
                               __ATOMIC_RELEASE, __HIP_MEMORY_SCOPE_AGENT);
        return;
    }

    // ================= REC ROLE (r5 core, verified) =================
    const int bt = blockIdx.x - 1024;
    unsigned int* flagp = flags + bt * 32;

    const int gate = m15 & 3;
    const float* Wsel = (gate == 0) ? Wf : (gate == 1) ? Wi : (gate == 2) ? Wc : Wo;
    const float ascale = (gate == 2) ? (-2.0f * L2E) : (-L2E);
    const int uAb = 8 * w + 2 * (m15 >> 2);

    bf16x8 Ah[2], Ae[2];
    #pragma unroll
    for (int tau = 0; tau < 2; ++tau) {
        const int uA = uAb + tau;
        #pragma unroll
        for (int j = 0; j < 4; ++j) {
            Ah[tau][j]     = (short)f2bf(ascale * Wsel[(4 * g + j) * UNITS_ + uA]);
            Ah[tau][j + 4] = (short)f2bf(ascale * Wsel[(16 + 4 * g + j) * UNITS_ + uA]);
            Ae[tau][j]     = (short)f2bf(ascale * Wsel[(32 + 4 * g + j) * UNITS_ + uA]);
            Ae[tau][j + 4] = 0;
        }
    }
    f32x4 bias[2];
    #pragma unroll
    for (int tau = 0; tau < 2; ++tau) {
        const int u = 8 * w + 2 * g + tau;
        bias[tau][0] = -L2E * bfv[u];
        bias[tau][1] = -L2E * biv[u];
        bias[tau][2] = -2.0f * L2E * bcv[u];
        bias[tau][3] = -L2E * bov[u];
    }

    // wait for chunk 0; prefetch flag of chunk 1
    unsigned fut;
    do {
        fut = __hip_atomic_load(flagp, __ATOMIC_ACQUIRE, __HIP_MEMORY_SCOPE_AGENT);
        if (fut != MAGIC) __builtin_amdgcn_s_sleep(1);
    } while (fut != MAGIC);
    fut = __hip_atomic_load(flagp + 1, __ATOMIC_ACQUIRE, __HIP_MEMORY_SCOPE_AGENT);

    const uint2* ep = (const uint2*)e_ws + (size_t)bt * T_ * 64 + lane;
    uint2 ering[4];
    #pragma unroll
    for (int s = 0; s < 4; ++s) ering[s] = ep[(size_t)s * 64];

    for (int i = tid; i < 2 * 16 * 36 / 2; i += 256) ((unsigned*)hx)[i] = 0;
    __syncthreads();

    float c0 = 0.f, c1 = 0.f, hf0 = 0.f, hf1 = 0.f;

    auto cell = [&](const f32x4& acc, float& cst, float& hf) {
        float Ef = __builtin_amdgcn_exp2f(acc[0]);
        float Ei = __builtin_amdgcn_exp2f(acc[1]);
        float Ec = __builtin_amdgcn_exp2f(acc[2]);
        float Eo = __builtin_amdgcn_exp2f(acc[3]);
        float Pf = 1.f + Ef, Pi = 1.f + Ei, Pc = 1.f + Ec, Po = 1.f + Eo;
        float Mc = 1.f - Ec;
        float t1 = Pi * Pc;
        float num = fmaf(cst, t1, Pf * Mc);
        float den = Pf * t1;
        float cn = num * __builtin_amdgcn_rcpf(den);
        cst = cn;
        float Eh = __builtin_amdgcn_exp2f(cn * (-2.0f * L2E));
        float Mh = 1.f - Eh;
        float d2 = (1.f + Eh) * Po;
        hf = Mh * __builtin_amdgcn_rcpf(d2);
    };
    auto mkBe = [](uint2 ev) -> bf16x8 {
        return bf16x8{(short)(ev.x & 0xffff), (short)(ev.x >> 16),
                      (short)(ev.y & 0xffff), (short)(ev.y >> 16), 0, 0, 0, 0};
    };

    f32x4 Fe0, Fe1;
    {
        bf16x8 Be = mkBe(ering[0]);
        Fe0 = __builtin_amdgcn_mfma_f32_16x16x32_bf16(Ae[0], Be, bias[0], 0, 0, 0);
        Fe1 = __builtin_amdgcn_mfma_f32_16x16x32_bf16(Ae[1], Be, bias[1], 0, 0, 0);
    }

    #pragma unroll 1
    for (int t = 0; t < T_; t += 4) {
        #pragma unroll
        for (int s = 0; s < 4; ++s) {
            const int u = t + s;
            const unsigned short* hrow = &hx[u & 1][m15][0];
            ushort4 hlo = *(const ushort4*)(hrow + 4 * g);
            ushort4 hhi = *(const ushort4*)(hrow + 16 + 4 * g);
            bf16x8 Bh = {(short)hlo.x, (short)hlo.y, (short)hlo.z, (short)hlo.w,
                         (short)hhi.x, (short)hhi.y, (short)hhi.z, (short)hhi.w};
            f32x4 a0 = __builtin_amdgcn_mfma_f32_16x16x32_bf16(Ah[0], Bh, Fe0, 0, 0, 0);
            f32x4 a1 = __builtin_amdgcn_mfma_f32_16x16x32_bf16(Ah[1], Bh, Fe1, 0, 0, 0);

            int tn = (u + 4 < T_) ? u + 4 : T_ - 1;
            // chunk-boundary gate: register-check a prefetched flag
            if ((tn & 7) == 0) {
                const int c = tn >> 3;
                while (fut != MAGIC) {
                    __builtin_amdgcn_s_sleep(1);
                    fut = __hip_atomic_load(flagp + c, __ATOMIC_ACQUIRE,
                                            __HIP_MEMORY_SCOPE_AGENT);
                }
                fut = (c < 31) ? __hip_atomic_load(flagp + c + 1, __ATOMIC_ACQUIRE,
                                                   __HIP_MEMORY_SCOPE_AGENT)
                               : MAGIC;
            }
            uint2 ev = ering[(s + 1) & 3];
            ering[s] = ep[(size_t)tn * 64];
            bf16x8 Be = mkBe(ev);
            Fe0 = __builtin_amdgcn_mfma_f32_16x16x32_bf16(Ae[0], Be, bias[0], 0, 0, 0);
            Fe1 = __builtin_amdgcn_mfma_f32_16x16x32_bf16(Ae[1], Be, bias[1], 0, 0, 0);

            cell(a0, c0, hf0);
            cell(a1, c1, hf1);
            unsigned pk;
            asm("v_cvt_pk_bf16_f32 %0, %1, %2" : "=v"(pk) : "v"(hf0), "v"(hf1));
            *(unsigned*)&hx[(u + 1) & 1][m15][8 * w + 2 * g] = pk;

            asm volatile("s_waitcnt lgkmcnt(0)\n\ts_barrier" ::: "memory");
        }
    }

    // reset this tile's flags for the next (replayed) launch
    asm volatile("s_waitcnt vmcnt(0)" ::: "memory");
    if (tid < 32) flagp[tid] = 0u;

    float p = hf0 * Wout[8 * w + 2 * g] + hf1 * Wout[8 * w + 2 * g + 1];
    p += __shfl_xor(p, 16, 64);
    p += __shfl_xor(p, 32, 64);
    if (lane < 16) pred[w][lane] = p;
    __syncthreads();
    if (tid < 16)
        out[bt * 16 + tid] = fast_sigmoid(pred[0][tid] + pred[1][tid] +
                                          pred[2][tid] + pred[3][tid] + bout[0]);
}

extern "C" void kernel_launch(void* const* d_in, const int* in_sizes, int n_in,
                              void* d_out, int out_size, void* d_ws, size_t ws_size,
                              hipStream_t stream) {
    const float* x    = (const float*)d_in[0];
    const float* Wemb = (const float*)d_in[1];
    const float* bemb = (const float*)d_in[2];
    const float* Wf   = (const float*)d_in[3];
    const float* bfv  = (const float*)d_in[4];
    const float* Wi   = (const float*)d_in[5];
    const float* biv  = (const float*)d_in[6];
    const float* Wc   = (const float*)d_in[7];
    const float* bcv  = (const float*)d_in[8];
    const float* Wo   = (const float*)d_in[9];
    const float* bov  = (const float*)d_in[10];
    const float* Wout = (const float*)d_in[11];
    const float* bout = (const float*)d_in[12];
    float* out = (float*)d_out;
    unsigned int* e_ws  = (unsigned int*)d_ws;                    // 16 MiB
    unsigned int* flags = e_ws + (16u << 20) / 4;                 // 128*32 uints

    hipLaunchKernelGGL(lstm_all, dim3(1024 + 128), dim3(256), 0, stream,
                       x, Wemb, bemb, Wf, bfv, Wi, biv, Wc, bcv, Wo, bov,
                       Wout, bout, e_ws, flags, out);
}

// Round 12
// 89.901 us; speedup vs baseline: 2.6363x; 2.6363x over previous
//
#include <hip/hip_runtime.h>

#define B_ 2048
#define T_ 256
#define F_ 64
#define EMB_ 16
#define UNITS_ 32
#define L2E 1.44269504f

typedef __attribute__((ext_vector_type(8))) short bf16x8;
typedef __attribute__((ext_vector_type(4))) float f32x4;

__device__ __forceinline__ unsigned short f2bf(float f) {  // RNE float->bf16
    unsigned u = __float_as_uint(f);
    return (unsigned short)((u + 0x7FFFu + ((u >> 16) & 1u)) >> 16);
}
__device__ __forceinline__ float fast_sigmoid(float x) {
    return __builtin_amdgcn_rcpf(1.0f + __builtin_amdgcn_exp2f(-L2E * x));
}

// ---------------- Kernel 1: embedding via MFMA (r5 verbatim, ~HBM floor) ----
__global__ __launch_bounds__(64) void embed_mfma(
    const float* __restrict__ x, const float* __restrict__ Wemb,
    const float* __restrict__ bemb, unsigned int* __restrict__ e_ws)
{
    __shared__ unsigned short slab[2][16][72];

    const int lane = threadIdx.x;
    const int g = lane >> 4, c = lane & 15;
    const int tile = blockIdx.x >> 5;
    const int t0 = (blockIdx.x & 31) * 8;

    bf16x8 A1, A2;
    #pragma unroll
    for (int j = 0; j < 4; ++j) {
        A1[j]     = (short)f2bf(Wemb[(4 * g + j) * EMB_ + c]);
        A1[j + 4] = (short)f2bf(Wemb[(16 + 4 * g + j) * EMB_ + c]);
        A2[j]     = (short)f2bf(Wemb[(32 + 4 * g + j) * EMB_ + c]);
        A2[j + 4] = (short)f2bf(Wemb[(48 + 4 * g + j) * EMB_ + c]);
    }
    f32x4 bc;
    #pragma unroll
    for (int r = 0; r < 4; ++r) bc[r] = bemb[4 * g + r];

    const int sr = lane >> 2, sc = lane & 3;
    const float* xs = x + (size_t)(tile * 16 + sr) * T_ * F_ + sc * 16;

    float4 rld[4], nld[4];
    {
        const float4* p = (const float4*)(xs + (size_t)t0 * F_);
        rld[0] = p[0]; rld[1] = p[1]; rld[2] = p[2]; rld[3] = p[3];
    }

    #pragma unroll
    for (int i = 0; i < 9; ++i) {
        if (i < 7) {
            const float4* p = (const float4*)(xs + (size_t)(t0 + i + 1) * F_);
            nld[0] = p[0]; nld[1] = p[1]; nld[2] = p[2]; nld[3] = p[3];
        }
        if (i < 8) {
            const float* f = (const float*)rld;
            unsigned u[8];
            #pragma unroll
            for (int k = 0; k < 8; ++k)
                u[k] = (unsigned)f2bf(f[2 * k]) | ((unsigned)f2bf(f[2 * k + 1]) << 16);
            uint4* d = (uint4*)&slab[i & 1][sr][sc * 16];
            d[0] = make_uint4(u[0], u[1], u[2], u[3]);
            d[1] = make_uint4(u[4], u[5], u[6], u[7]);
        }
        if (i > 0) {
            const unsigned short* row = &slab[(i - 1) & 1][c][0];
            ushort4 l1 = *(const ushort4*)(row + 4 * g);
            ushort4 h1 = *(const ushort4*)(row + 16 + 4 * g);
            ushort4 l2 = *(const ushort4*)(row + 32 + 4 * g);
            ushort4 h2 = *(const ushort4*)(row + 48 + 4 * g);
            bf16x8 B1 = {(short)l1.x, (short)l1.y, (short)l1.z, (short)l1.w,
                         (short)h1.x, (short)h1.y, (short)h1.z, (short)h1.w};
            bf16x8 B2 = {(short)l2.x, (short)l2.y, (short)l2.z, (short)l2.w,
                         (short)h2.x, (short)h2.y, (short)h2.z, (short)h2.w};
            f32x4 acc = __builtin_amdgcn_mfma_f32_16x16x32_bf16(A1, B1, bc, 0, 0, 0);
            acc = __builtin_amdgcn_mfma_f32_16x16x32_bf16(A2, B2, acc, 0, 0, 0);
            unsigned u0 = (unsigned)f2bf(fast_sigmoid(acc[0])) |
                          ((unsigned)f2bf(fast_sigmoid(acc[1])) << 16);
            unsigned u1 = (unsigned)f2bf(fast_sigmoid(acc[2])) |
                          ((unsigned)f2bf(fast_sigmoid(acc[3])) << 16);
            size_t idx = (((size_t)tile * T_ + (t0 + i - 1)) * 64 + lane) * 2;
            *(uint2*)(e_ws + idx) = make_uint2(u0, u1);
        }
        #pragma unroll
        for (int k = 0; k < 4; ++k) rld[k] = nld[k];
    }
}

// ---------------- Kernel 2: LSTM recurrence, 8 waves, 1 cell/lane ------------
// 128 WGs x 8 waves (2 waves/SIMD). Wave w owns M-tile w = 4 gates of units
// [4w,4w+4): row m -> (gate m&3, unit 4w+(m>>2)). Lane (g,m15) owns ONE cell
// (unit 4w+g, batch m15), gates in acc rows 4g+r -> r. Minimal per-wave step:
// 2 ds_read_b64 -> 1 on-path MFMA -> 1 cell -> 1 ds_write_b16; the co-SIMD
// wave's issue fills this wave's exchange/MFMA/cell latency. Fe precomputed
// one step ahead; lgkm-only barrier; A/bias pre-scaled (-L2E, c rows -2L2E).
__global__ __launch_bounds__(512) void lstm_rec(
    const float* __restrict__ Wf, const float* __restrict__ bfv,
    const float* __restrict__ Wi, const float* __restrict__ biv,
    const float* __restrict__ Wc, const float* __restrict__ bcv,
    const float* __restrict__ Wo, const float* __restrict__ bov,
    const float* __restrict__ Wout, const float* __restrict__ bout,
    const unsigned int* __restrict__ e_ws, float* __restrict__ out)
{
    __shared__ unsigned short hx[2][16][36];   // [parity][batch][unit], pad 36
    __shared__ float pred[8][16];

    const int tid = threadIdx.x;
    const int w = tid >> 6;          // 0..7
    const int lane = tid & 63;
    const int g = lane >> 4, m15 = lane & 15;
    const int bt = blockIdx.x;

    const int gate = m15 & 3;
    const float* Wsel = (gate == 0) ? Wf : (gate == 1) ? Wi : (gate == 2) ? Wc : Wo;
    const float ascale = (gate == 2) ? (-2.0f * L2E) : (-L2E);
    const int uA = 4 * w + (m15 >> 2);   // A-row unit

    bf16x8 Ah, Ae;
    #pragma unroll
    for (int j = 0; j < 4; ++j) {
        Ah[j]     = (short)f2bf(ascale * Wsel[(4 * g + j) * UNITS_ + uA]);
        Ah[j + 4] = (short)f2bf(ascale * Wsel[(16 + 4 * g + j) * UNITS_ + uA]);
        Ae[j]     = (short)f2bf(ascale * Wsel[(32 + 4 * g + j) * UNITS_ + uA]);
        Ae[j + 4] = 0;
    }
    const int cu = 4 * w + g;            // this lane's cell unit
    f32x4 bias;
    bias[0] = -L2E * bfv[cu];
    bias[1] = -L2E * biv[cu];
    bias[2] = -2.0f * L2E * bcv[cu];
    bias[3] = -L2E * bov[cu];

    const uint2* ep = (const uint2*)e_ws + (size_t)bt * T_ * 64 + lane;
    uint2 ering[4];
    #pragma unroll
    for (int s = 0; s < 4; ++s) ering[s] = ep[(size_t)s * 64];

    for (int i = tid; i < 2 * 16 * 36 / 2; i += 512) ((unsigned*)hx)[i] = 0;
    __syncthreads();

    float cst = 0.f, hf = 0.f;

    auto cell = [&](const f32x4& acc) {
        float Ef = __builtin_amdgcn_exp2f(acc[0]);
        float Ei = __builtin_amdgcn_exp2f(acc[1]);
        float Ec = __builtin_amdgcn_exp2f(acc[2]);
        float Eo = __builtin_amdgcn_exp2f(acc[3]);
        float Pf = 1.f + Ef, Pi = 1.f + Ei, Pc = 1.f + Ec, Po = 1.f + Eo;
        float Mc = 1.f - Ec;
        float t1 = Pi * Pc;
        float num = fmaf(cst, t1, Pf * Mc);
        float den = Pf * t1;
        float cn = num * __builtin_amdgcn_rcpf(den);
        cst = cn;
        float Eh = __builtin_amdgcn_exp2f(cn * (-2.0f * L2E));
        float Mh = 1.f - Eh;
        float d2 = (1.f + Eh) * Po;
        hf = Mh * __builtin_amdgcn_rcpf(d2);
    };
    auto mkBe = [](uint2 ev) -> bf16x8 {
        return bf16x8{(short)(ev.x & 0xffff), (short)(ev.x >> 16),
                      (short)(ev.y & 0xffff), (short)(ev.y >> 16), 0, 0, 0, 0};
    };

    f32x4 Fe;
    {
        bf16x8 Be = mkBe(ering[0]);
        Fe = __builtin_amdgcn_mfma_f32_16x16x32_bf16(Ae, Be, bias, 0, 0, 0);
    }

    #pragma unroll 1
    for (int t = 0; t < T_; t += 4) {
        #pragma unroll
        for (int s = 0; s < 4; ++s) {
            const int u = t + s;
            // h-dependent path: 2 ds_read_b64 -> ONE mfma -> cell
            const unsigned short* hrow = &hx[u & 1][m15][0];
            ushort4 hlo = *(const ushort4*)(hrow + 4 * g);
            ushort4 hhi = *(const ushort4*)(hrow + 16 + 4 * g);
            bf16x8 Bh = {(short)hlo.x, (short)hlo.y, (short)hlo.z, (short)hlo.w,
                         (short)hhi.x, (short)hhi.y, (short)hhi.z, (short)hhi.w};
            f32x4 acc = __builtin_amdgcn_mfma_f32_16x16x32_bf16(Ah, Bh, Fe, 0, 0, 0);

            // off-path: next-step Fe, ring refill
            int tn = (u + 4 < T_) ? u + 4 : T_ - 1;
            uint2 ev = ering[(s + 1) & 3];
            ering[s] = ep[(size_t)tn * 64];
            bf16x8 Be = mkBe(ev);
            Fe = __builtin_amdgcn_mfma_f32_16x16x32_bf16(Ae, Be, bias, 0, 0, 0);

            cell(acc);
            hx[(u + 1) & 1][m15][cu] = f2bf(hf);

            // lgkm-only barrier: global e-prefetch stays in flight
            asm volatile("s_waitcnt lgkmcnt(0)\n\ts_barrier" ::: "memory");
        }
    }

    // ---- output projection: sum over 32 units ----
    float p = hf * Wout[cu];
    p += __shfl_xor(p, 16, 64);
    p += __shfl_xor(p, 32, 64);
    if (lane < 16) pred[w][lane] = p;
    __syncthreads();
    if (tid < 16) {
        float sum = bout[0];
        #pragma unroll
        for (int ww = 0; ww < 8; ++ww) sum += pred[ww][tid];
        out[bt * 16 + tid] = fast_sigmoid(sum);
    }
}

extern "C" void kernel_launch(void* const* d_in, const int* in_sizes, int n_in,
                              void* d_out, int out_size, void* d_ws, size_t ws_size,
                              hipStream_t stream) {
    const float* x    = (const float*)d_in[0];
    const float* Wemb = (const float*)d_in[1];
    const float* bemb = (const float*)d_in[2];
    const float* Wf   = (const float*)d_in[3];
    const float* bfv  = (const float*)d_in[4];
    const float* Wi   = (const float*)d_in[5];
    const float* biv  = (const float*)d_in[6];
    const float* Wc   = (const float*)d_in[7];
    const float* bcv  = (const float*)d_in[8];
    const float* Wo   = (const float*)d_in[9];
    const float* bov  = (const float*)d_in[10];
    const float* Wout = (const float*)d_in[11];
    const float* bout = (const float*)d_in[12];
    float* out = (float*)d_out;
    unsigned int* e_ws = (unsigned int*)d_ws;   // 16 MiB fragment-layout e

    hipLaunchKernelGGL(embed_mfma, dim3(128 * 32), dim3(64), 0, stream,
                       x, Wemb, bemb, e_ws);
    hipLaunchKernelGGL(lstm_rec, dim3(B_ / 16), dim3(512), 0, stream,
                       Wf, bfv, Wi, biv, Wc, bcv, Wo, bov, Wout, bout,
                       (const unsigned int*)e_ws, out);
}